// Round 1
// baseline (2011.642 us; speedup 1.0000x reference)
//
#include <hip/hip_runtime.h>
#include <math.h>

#define NQ 40000
#define NV 52500
#define D 256
#define NHEAD 8
#define HD 32

// ---------------------------------------------------------------- LN1 + qp
__global__ __launch_bounds__(256) void k_ln1(const float* __restrict__ qin,
                                             const float* __restrict__ qpos,
                                             const float* __restrict__ g,
                                             const float* __restrict__ b,
                                             float* __restrict__ id_out,
                                             float* __restrict__ qp_out) {
  int wave = threadIdx.x >> 6;
  int lane = threadIdx.x & 63;
  int row  = blockIdx.x * 4 + wave;
  if (row >= NQ) return;
  float4 x = ((const float4*)(qin + (size_t)row * D))[lane];
  float s  = x.x + x.y + x.z + x.w;
  float ss = x.x*x.x + x.y*x.y + x.z*x.z + x.w*x.w;
  for (int o = 32; o > 0; o >>= 1) { s += __shfl_down(s, o); ss += __shfl_down(ss, o); }
  s  = __shfl(s, 0);
  ss = __shfl(ss, 0);
  float m   = s * (1.0f / 256.0f);
  float var = ss * (1.0f / 256.0f) - m * m;
  float rs  = rsqrtf(var + 1e-5f);
  float4 gg = ((const float4*)g)[lane];
  float4 bb = ((const float4*)b)[lane];
  float4 qn;
  qn.x = (x.x - m) * rs * gg.x + bb.x;
  qn.y = (x.y - m) * rs * gg.y + bb.y;
  qn.z = (x.z - m) * rs * gg.z + bb.z;
  qn.w = (x.w - m) * rs * gg.w + bb.w;
  ((float4*)(id_out + (size_t)row * D))[lane] = qn;
  float4 p = ((const float4*)(qpos + (size_t)row * D))[lane];
  qn.x += p.x; qn.y += p.y; qn.z += p.z; qn.w += p.w;
  ((float4*)(qp_out + (size_t)row * D))[lane] = qn;
}

// ------------------------------------------- offsets+attn GEMM, softmax, loc
__global__ __launch_bounds__(256) void k_offattn(const float* __restrict__ qp,
                                                 const float* __restrict__ Woff,
                                                 const float* __restrict__ boff,
                                                 const float* __restrict__ Wattn,
                                                 const float* __restrict__ battn,
                                                 const float* __restrict__ refp,
                                                 float* __restrict__ loc_out,
                                                 float* __restrict__ aw_out) {
  __shared__ float qs[8][D];
  __shared__ float res[8][288];
  int q0 = blockIdx.x * 8;
  for (int r = 0; r < 8; ++r)
    qs[r][threadIdx.x] = qp[(size_t)(q0 + r) * D + threadIdx.x];
  __syncthreads();

  for (int jj = threadIdx.x; jj < 288; jj += 256) {
    const float* Wp; int ld; float bias;
    if (jj < 192) { Wp = Woff + jj;        ld = 192; bias = boff[jj]; }
    else          { Wp = Wattn + (jj-192); ld = 96;  bias = battn[jj-192]; }
    float acc[8];
#pragma unroll
    for (int r = 0; r < 8; ++r) acc[r] = 0.0f;
    for (int k = 0; k < D; ++k) {
      float w = Wp[(size_t)k * ld];
#pragma unroll
      for (int r = 0; r < 8; ++r) acc[r] += qs[r][k] * w;
    }
#pragma unroll
    for (int r = 0; r < 8; ++r) res[r][jj] = acc[r] + bias;
  }
  __syncthreads();

  // softmax over 12 per (row, head)
  if (threadIdx.x < 64) {
    int r = threadIdx.x >> 3, h = threadIdx.x & 7;
    float* lg = &res[r][192 + h * 12];
    float mx = lg[0];
#pragma unroll
    for (int i = 1; i < 12; ++i) mx = fmaxf(mx, lg[i]);
    float e[12]; float sum = 0.0f;
#pragma unroll
    for (int i = 0; i < 12; ++i) { e[i] = expf(lg[i] - mx); sum += e[i]; }
    float inv = 1.0f / sum;
#pragma unroll
    for (int i = 0; i < 12; ++i)
      aw_out[(size_t)(q0 + r) * 96 + h * 12 + i] = e[i] * inv;
  }

  // loc = ref + off / (W,H)
  const float dims[3] = {200.0f, 100.0f, 50.0f};   // square levels
  for (int idx = threadIdx.x; idx < 8 * 192; idx += 256) {
    int r = idx / 192, j = idx % 192;
    int pi = j >> 1, c = j & 1;
    int l = (pi >> 2) % 3;
    float dim = dims[l];
    float rp = refp[((size_t)(q0 + r) * 3 + l) * 2 + c];
    loc_out[(size_t)(q0 + r) * 192 + j] = rp + res[r][j] / dim;
  }
}

// ---------------------------------------------------------------- value proj
__global__ __launch_bounds__(256) void k_vproj(const float* __restrict__ val,
                                               const float* __restrict__ Wv,
                                               const float* __restrict__ bv,
                                               float* __restrict__ vout) {
  __shared__ float as[8][D];
  int q0 = blockIdx.x * 8;
#pragma unroll
  for (int r = 0; r < 8; ++r) {
    int row = q0 + r;
    as[r][threadIdx.x] = (row < NV) ? val[(size_t)row * D + threadIdx.x] : 0.0f;
  }
  __syncthreads();
  int j = threadIdx.x;
  float acc[8];
#pragma unroll
  for (int r = 0; r < 8; ++r) acc[r] = 0.0f;
  for (int k = 0; k < D; ++k) {
    float w = Wv[(size_t)k * D + j];
#pragma unroll
    for (int r = 0; r < 8; ++r) acc[r] += as[r][k] * w;
  }
  float bj = bv[j];
#pragma unroll
  for (int r = 0; r < 8; ++r) {
    int row = q0 + r;
    if (row < NV) vout[(size_t)row * D + j] = acc[r] + bj;
  }
}

// ----------------------------------------------------------- deform sampling
__global__ __launch_bounds__(256) void k_sample(const float* __restrict__ vproj,
                                                const float* __restrict__ loc,
                                                const float* __restrict__ aw,
                                                float* __restrict__ smp) {
  int unit = threadIdx.x >> 5;   // 0..7
  int d    = threadIdx.x & 31;
  int qh   = blockIdx.x * 8 + unit;
  int q = qh >> 3, h = qh & 7;
  float acc = 0.0f;
  const int Hs[3] = {200, 100, 50};
  const int Ws[3] = {200, 100, 50};
  const int Ss[3] = {0, 40000, 50000};
#pragma unroll
  for (int l = 0; l < 3; ++l) {
    const int H = Hs[l], W = Ws[l], st = Ss[l];
#pragma unroll
    for (int p = 0; p < 4; ++p) {
      size_t base = (size_t)q * 192 + (((h * 3 + l) * 4 + p) << 1);
      float lx = loc[base], ly = loc[base + 1];
      float a  = aw[(size_t)q * 96 + h * 12 + l * 4 + p];
      float fx = lx * (float)W - 0.5f;
      float fy = ly * (float)H - 0.5f;
      float x0f = floorf(fx), y0f = floorf(fy);
      float tx = fx - x0f, ty = fy - y0f;
      int x0 = (int)x0f, y0 = (int)y0f;
#pragma unroll
      for (int dy = 0; dy < 2; ++dy) {
#pragma unroll
        for (int dx = 0; dx < 2; ++dx) {
          int xi = x0 + dx, yi = y0 + dy;
          if (xi >= 0 && xi < W && yi >= 0 && yi < H) {
            float w = (dx ? tx : 1.0f - tx) * (dy ? ty : 1.0f - ty);
            float gv = vproj[((size_t)(st + yi * W + xi)) * D + h * HD + d];
            acc += a * w * gv;
          }
        }
      }
    }
  }
  smp[(size_t)q * D + h * HD + d] = acc;
}

// ------------------------------------------------- out proj + both residuals
__global__ __launch_bounds__(256) void k_outproj(const float* __restrict__ smp,
                                                 const float* __restrict__ Wout,
                                                 const float* __restrict__ bout,
                                                 const float* __restrict__ iden,
                                                 const float* __restrict__ query,
                                                 float* __restrict__ x_out) {
  __shared__ float as[8][D];
  int q0 = blockIdx.x * 8;
#pragma unroll
  for (int r = 0; r < 8; ++r)
    as[r][threadIdx.x] = smp[(size_t)(q0 + r) * D + threadIdx.x];
  __syncthreads();
  int j = threadIdx.x;
  float acc[8];
#pragma unroll
  for (int r = 0; r < 8; ++r) acc[r] = 0.0f;
  for (int k = 0; k < D; ++k) {
    float w = Wout[(size_t)k * D + j];
#pragma unroll
    for (int r = 0; r < 8; ++r) acc[r] += as[r][k] * w;
  }
  float bj = bout[j];
#pragma unroll
  for (int r = 0; r < 8; ++r) {
    size_t off = (size_t)(q0 + r) * D + j;
    x_out[off] = query[off] + iden[off] + acc[r] + bj;
  }
}

// ------------------------------------------------------- LN2 + FFN, in place
__global__ __launch_bounds__(256) void k_ffn(float* __restrict__ xio,
                                             const float* __restrict__ g2,
                                             const float* __restrict__ b2n,
                                             const float* __restrict__ W1,
                                             const float* __restrict__ b1,
                                             const float* __restrict__ W2,
                                             const float* __restrict__ b2) {
  __shared__ float hs[8][D];       // 8 KB
  __shared__ float mid[8][1024];   // 32 KB
  int q0 = blockIdx.x * 8;
  int wave = threadIdx.x >> 6, lane = threadIdx.x & 63;

  for (int r = wave; r < 8; r += 4) {
    int row = q0 + r;
    float4 x = ((const float4*)(xio + (size_t)row * D))[lane];
    float s  = x.x + x.y + x.z + x.w;
    float ss = x.x*x.x + x.y*x.y + x.z*x.z + x.w*x.w;
    for (int o = 32; o > 0; o >>= 1) { s += __shfl_down(s, o); ss += __shfl_down(ss, o); }
    s  = __shfl(s, 0);
    ss = __shfl(ss, 0);
    float m   = s * (1.0f / 256.0f);
    float var = ss * (1.0f / 256.0f) - m * m;
    float rs  = rsqrtf(var + 1e-5f);
    float4 gg = ((const float4*)g2)[lane];
    float4 bb = ((const float4*)b2n)[lane];
    hs[r][lane*4+0] = (x.x - m) * rs * gg.x + bb.x;
    hs[r][lane*4+1] = (x.y - m) * rs * gg.y + bb.y;
    hs[r][lane*4+2] = (x.z - m) * rs * gg.z + bb.z;
    hs[r][lane*4+3] = (x.w - m) * rs * gg.w + bb.w;
  }
  __syncthreads();

  for (int cc = 0; cc < 4; ++cc) {
    int j = cc * 256 + threadIdx.x;
    float acc[8];
#pragma unroll
    for (int r = 0; r < 8; ++r) acc[r] = 0.0f;
    for (int k = 0; k < D; ++k) {
      float w = W1[(size_t)k * 1024 + j];
#pragma unroll
      for (int r = 0; r < 8; ++r) acc[r] += hs[r][k] * w;
    }
    float bj = b1[j];
#pragma unroll
    for (int r = 0; r < 8; ++r) {
      float t = acc[r] + bj;
      mid[r][j] = 0.5f * t * (1.0f + erff(t * 0.70710678118f));
    }
  }
  __syncthreads();

  int i = threadIdx.x;
  float acc2[8];
#pragma unroll
  for (int r = 0; r < 8; ++r) acc2[r] = 0.0f;
  for (int k = 0; k < 1024; ++k) {
    float w2 = W2[(size_t)k * D + i];
#pragma unroll
    for (int r = 0; r < 8; ++r) acc2[r] += mid[r][k] * w2;
  }
  float bi = b2[i];
#pragma unroll
  for (int r = 0; r < 8; ++r) {
    size_t off = (size_t)(q0 + r) * D + i;
    xio[off] = xio[off] + acc2[r] + bi;
  }
}

// ---------------------------------------------------------------------------
extern "C" void kernel_launch(void* const* d_in, const int* in_sizes, int n_in,
                              void* d_out, int out_size, void* d_ws, size_t ws_size,
                              hipStream_t stream) {
  const float* query  = (const float*)d_in[0];
  const float* value  = (const float*)d_in[1];
  const float* qpos   = (const float*)d_in[2];
  const float* refp   = (const float*)d_in[3];
  // d_in[4] spatial_shapes, d_in[5] level_start_index: constants, hardcoded
  const float* n1g = (const float*)d_in[6];
  const float* n1b = (const float*)d_in[7];
  const float* Woff = (const float*)d_in[8];
  const float* boff = (const float*)d_in[9];
  const float* Wattn = (const float*)d_in[10];
  const float* battn = (const float*)d_in[11];
  const float* Wval = (const float*)d_in[12];
  const float* bval = (const float*)d_in[13];
  const float* Wout = (const float*)d_in[14];
  const float* bout = (const float*)d_in[15];
  const float* n2g = (const float*)d_in[16];
  const float* n2b = (const float*)d_in[17];
  const float* W1 = (const float*)d_in[18];
  const float* b1 = (const float*)d_in[19];
  const float* W2 = (const float*)d_in[20];
  const float* b2 = (const float*)d_in[21];

  float* out = (float*)d_out;
  float* ws  = (float*)d_ws;

  const size_t nqd = (size_t)NQ * D;          // 10.24M
  float* qp   = ws;                           // NQ*256
  float* iden = qp + nqd;                     // NQ*256
  float* locb = iden + nqd;                   // NQ*192
  float* awb  = locb + (size_t)NQ * 192;      // NQ*96
  float* vprj = awb + (size_t)NQ * 96;        // NV*256
  float* smp  = qp;                           // reuse qp after k_offattn

  k_ln1<<<NQ / 4, 256, 0, stream>>>(query, qpos, n1g, n1b, iden, qp);
  k_offattn<<<NQ / 8, 256, 0, stream>>>(qp, Woff, boff, Wattn, battn, refp, locb, awb);
  k_vproj<<<(NV + 7) / 8, 256, 0, stream>>>(value, Wval, bval, vprj);
  k_sample<<<NQ * NHEAD / 8, 256, 0, stream>>>(vprj, locb, awb, smp);
  k_outproj<<<NQ / 8, 256, 0, stream>>>(smp, Wout, bout, iden, query, out);
  k_ffn<<<NQ / 8, 256, 0, stream>>>(out, n2g, n2b, W1, b1, W2, b2);
}

// Round 2
// 756.149 us; speedup vs baseline: 2.6604x; 2.6604x over previous
//
#include <hip/hip_runtime.h>
#include <hip/hip_bf16.h>
#include <math.h>

#define NQ 40000
#define NV 52500
#define D 256
#define NHEAD 8
#define HD 32

using bf16x8 = __attribute__((ext_vector_type(8))) short;
using f32x4  = __attribute__((ext_vector_type(4))) float;

__device__ __forceinline__ short f2bf(float f) {
  union { __hip_bfloat16 h; short s; } u;
  u.h = __float2bfloat16(f);
  return u.s;
}

// ---------------------------------------------------- weight transpose->bf16
__global__ __launch_bounds__(256) void k_wt(const float* __restrict__ Wm,
                                            short* __restrict__ WT, int K, int N) {
  int idx = blockIdx.x * 256 + threadIdx.x;
  if (idx >= N * K) return;
  int n = idx / K, k = idx - n * K;
  WT[idx] = f2bf(Wm[(size_t)k * N + n]);
}

__global__ void k_catbias(const float* __restrict__ a, const float* __restrict__ b,
                          float* __restrict__ o) {
  int i = threadIdx.x;
  if (i < 192) o[i] = a[i];
  else if (i < 288) o[i] = b[i - 192];
}

// ---------------------------------------------------------------- LN1 + qp
__global__ __launch_bounds__(256) void k_ln1(const float* __restrict__ qin,
                                             const float* __restrict__ qpos,
                                             const float* __restrict__ g,
                                             const float* __restrict__ b,
                                             float* __restrict__ id_out,
                                             short* __restrict__ qp_out) {
  int wave = threadIdx.x >> 6;
  int lane = threadIdx.x & 63;
  int row  = blockIdx.x * 4 + wave;
  float4 x = ((const float4*)(qin + (size_t)row * D))[lane];
  float s  = x.x + x.y + x.z + x.w;
  float ss = x.x*x.x + x.y*x.y + x.z*x.z + x.w*x.w;
  for (int o = 32; o > 0; o >>= 1) { s += __shfl_down(s, o); ss += __shfl_down(ss, o); }
  s  = __shfl(s, 0);
  ss = __shfl(ss, 0);
  float m   = s * (1.0f / 256.0f);
  float var = ss * (1.0f / 256.0f) - m * m;
  float rs  = rsqrtf(var + 1e-5f);
  float4 gg = ((const float4*)g)[lane];
  float4 bb = ((const float4*)b)[lane];
  float4 qn;
  qn.x = (x.x - m) * rs * gg.x + bb.x;
  qn.y = (x.y - m) * rs * gg.y + bb.y;
  qn.z = (x.z - m) * rs * gg.z + bb.z;
  qn.w = (x.w - m) * rs * gg.w + bb.w;
  ((float4*)(id_out + (size_t)row * D))[lane] = qn;
  float4 p = ((const float4*)(qpos + (size_t)row * D))[lane];
  short4 o;
  o.x = f2bf(qn.x + p.x); o.y = f2bf(qn.y + p.y);
  o.z = f2bf(qn.z + p.z); o.w = f2bf(qn.w + p.w);
  ((short4*)(qp_out + (size_t)row * D))[lane] = o;
}

// ----------------------------------------------------------- LN2 -> bf16 h
__global__ __launch_bounds__(256) void k_ln2(const float* __restrict__ xin,
                                             const float* __restrict__ g,
                                             const float* __restrict__ b,
                                             short* __restrict__ h_out) {
  int wave = threadIdx.x >> 6;
  int lane = threadIdx.x & 63;
  int row  = blockIdx.x * 4 + wave;
  float4 x = ((const float4*)(xin + (size_t)row * D))[lane];
  float s  = x.x + x.y + x.z + x.w;
  float ss = x.x*x.x + x.y*x.y + x.z*x.z + x.w*x.w;
  for (int o = 32; o > 0; o >>= 1) { s += __shfl_down(s, o); ss += __shfl_down(ss, o); }
  s  = __shfl(s, 0);
  ss = __shfl(ss, 0);
  float m   = s * (1.0f / 256.0f);
  float var = ss * (1.0f / 256.0f) - m * m;
  float rs  = rsqrtf(var + 1e-5f);
  float4 gg = ((const float4*)g)[lane];
  float4 bb = ((const float4*)b)[lane];
  short4 o;
  o.x = f2bf((x.x - m) * rs * gg.x + bb.x);
  o.y = f2bf((x.y - m) * rs * gg.y + bb.y);
  o.z = f2bf((x.z - m) * rs * gg.z + bb.z);
  o.w = f2bf((x.w - m) * rs * gg.w + bb.w);
  ((short4*)(h_out + (size_t)row * D))[lane] = o;
}

// ----------------------------------------------------------- fp32 -> bf16
__global__ __launch_bounds__(256) void k_cvt(const float* __restrict__ in,
                                             short* __restrict__ out, int n4) {
  int i = blockIdx.x * 256 + threadIdx.x;
  if (i >= n4) return;
  float4 v = ((const float4*)in)[i];
  short4 o;
  o.x = f2bf(v.x); o.y = f2bf(v.y); o.z = f2bf(v.z); o.w = f2bf(v.w);
  ((short4*)out)[i] = o;
}

// --------------------------------------------------------------- MFMA GEMM
// C[M][N] = A[M][K](bf16) @ WT[N][K]^T(bf16) + bias
// EPI: 0 = store f32; 1 = gelu -> bf16; 2 = + R1 + R2 -> f32; 3 = Cf += v
template<int EPI>
__global__ __launch_bounds__(256) void k_gemm(const short* __restrict__ A,
                                              const short* __restrict__ WT,
                                              const float* __restrict__ bias,
                                              float* __restrict__ Cf,
                                              short* __restrict__ Cb,
                                              const float* __restrict__ R1,
                                              const float* __restrict__ R2,
                                              int M, int N, int K) {
  __shared__ short Al[64 * 40];
  __shared__ short Bl[64 * 40];
  const int tid = threadIdx.x;
  const int m0 = blockIdx.x * 64, n0 = blockIdx.y * 64;
  const int sr = tid >> 2, sc = (tid & 3) << 3;
  const int lane = tid & 63, w = tid >> 6;
  const int wm = (w >> 1) * 32, wn = (w & 1) * 32;
  const int lr = lane & 15, lk = (lane >> 4) << 3;

  const bf16x8* a0p = (const bf16x8*)&Al[(wm + lr) * 40 + lk];
  const bf16x8* a1p = (const bf16x8*)&Al[(wm + 16 + lr) * 40 + lk];
  const bf16x8* b0p = (const bf16x8*)&Bl[(wn + lr) * 40 + lk];
  const bf16x8* b1p = (const bf16x8*)&Bl[(wn + 16 + lr) * 40 + lk];

  const short* aSrc = (m0 + sr < M) ? A + (size_t)(m0 + sr) * K + sc : nullptr;
  const short* bSrc = (n0 + sr < N) ? WT + (size_t)(n0 + sr) * K + sc : nullptr;

  f32x4 acc00 = {0,0,0,0}, acc01 = {0,0,0,0}, acc10 = {0,0,0,0}, acc11 = {0,0,0,0};

  for (int k0 = 0; k0 < K; k0 += 32) {
    int4 av = {0,0,0,0}, bv = {0,0,0,0};
    if (aSrc) av = *(const int4*)(aSrc + k0);
    if (bSrc) bv = *(const int4*)(bSrc + k0);
    __syncthreads();
    *(int4*)&Al[sr * 40 + sc] = av;
    *(int4*)&Bl[sr * 40 + sc] = bv;
    __syncthreads();
    bf16x8 af0 = *a0p, af1 = *a1p, bf0 = *b0p, bf1 = *b1p;
    acc00 = __builtin_amdgcn_mfma_f32_16x16x32_bf16(af0, bf0, acc00, 0, 0, 0);
    acc01 = __builtin_amdgcn_mfma_f32_16x16x32_bf16(af0, bf1, acc01, 0, 0, 0);
    acc10 = __builtin_amdgcn_mfma_f32_16x16x32_bf16(af1, bf0, acc10, 0, 0, 0);
    acc11 = __builtin_amdgcn_mfma_f32_16x16x32_bf16(af1, bf1, acc11, 0, 0, 0);
  }

  const int er = (lane >> 4) << 2;
  const int ec = lane & 15;
#pragma unroll
  for (int i = 0; i < 2; ++i) {
#pragma unroll
    for (int j = 0; j < 2; ++j) {
      f32x4 acc = (i == 0) ? (j == 0 ? acc00 : acc01) : (j == 0 ? acc10 : acc11);
      int col = n0 + wn + j * 16 + ec;
      if (col >= N) continue;
      float bcol = bias[col];
#pragma unroll
      for (int r = 0; r < 4; ++r) {
        int row = m0 + wm + i * 16 + er + r;
        if (row >= M) continue;
        float v = acc[r] + bcol;
        size_t off = (size_t)row * N + col;
        if (EPI == 0) {
          Cf[off] = v;
        } else if (EPI == 1) {
          Cb[off] = f2bf(0.5f * v * (1.0f + erff(v * 0.70710678118f)));
        } else if (EPI == 2) {
          Cf[off] = v + R1[off] + R2[off];
        } else {
          Cf[off] += v;
        }
      }
    }
  }
}

// --------------------------------------------- softmax + loc from res rows
__global__ __launch_bounds__(256) void k_post(const float* __restrict__ res,
                                              const float* __restrict__ refp,
                                              float* __restrict__ loc_out,
                                              float* __restrict__ aw_out) {
  int t = blockIdx.x * 256 + threadIdx.x;
  if (t >= NQ * 8) return;
  int q = t >> 3, h = t & 7;
  const float* rr = res + (size_t)q * 288;
  const float* lg = rr + 192 + h * 12;
  float mx = lg[0];
#pragma unroll
  for (int i = 1; i < 12; ++i) mx = fmaxf(mx, lg[i]);
  float e[12]; float sum = 0.0f;
#pragma unroll
  for (int i = 0; i < 12; ++i) { e[i] = expf(lg[i] - mx); sum += e[i]; }
  float inv = 1.0f / sum;
#pragma unroll
  for (int i = 0; i < 12; ++i)
    aw_out[(size_t)q * 96 + h * 12 + i] = e[i] * inv;

  const float dims[3] = {200.0f, 100.0f, 50.0f};
#pragma unroll
  for (int l = 0; l < 3; ++l) {
    float rx = refp[((size_t)q * 3 + l) * 2 + 0];
    float ry = refp[((size_t)q * 3 + l) * 2 + 1];
    float invd = 1.0f / dims[l];
#pragma unroll
    for (int p = 0; p < 4; ++p) {
      int j = ((h * 3 + l) * 4 + p) * 2;
      loc_out[(size_t)q * 192 + j + 0] = rx + rr[j + 0] * invd;
      loc_out[(size_t)q * 192 + j + 1] = ry + rr[j + 1] * invd;
    }
  }
}

// ----------------------------------------------------------- deform sampling
__global__ __launch_bounds__(256) void k_sample(const float* __restrict__ vproj,
                                                const float* __restrict__ loc,
                                                const float* __restrict__ aw,
                                                short* __restrict__ smp) {
  int unit = threadIdx.x >> 5;   // 0..7
  int d    = threadIdx.x & 31;
  int qh   = blockIdx.x * 8 + unit;
  int q = qh >> 3, h = qh & 7;
  float acc = 0.0f;
  const int Hs[3] = {200, 100, 50};
  const int Ws[3] = {200, 100, 50};
  const int Ss[3] = {0, 40000, 50000};
#pragma unroll
  for (int l = 0; l < 3; ++l) {
    const int H = Hs[l], W = Ws[l], st = Ss[l];
#pragma unroll
    for (int p = 0; p < 4; ++p) {
      size_t base = (size_t)q * 192 + (((h * 3 + l) * 4 + p) << 1);
      float lx = loc[base], ly = loc[base + 1];
      float a  = aw[(size_t)q * 96 + h * 12 + l * 4 + p];
      float fx = lx * (float)W - 0.5f;
      float fy = ly * (float)H - 0.5f;
      float x0f = floorf(fx), y0f = floorf(fy);
      float tx = fx - x0f, ty = fy - y0f;
      int x0 = (int)x0f, y0 = (int)y0f;
#pragma unroll
      for (int dy = 0; dy < 2; ++dy) {
#pragma unroll
        for (int dx = 0; dx < 2; ++dx) {
          int xi = x0 + dx, yi = y0 + dy;
          if (xi >= 0 && xi < W && yi >= 0 && yi < H) {
            float wgt = (dx ? tx : 1.0f - tx) * (dy ? ty : 1.0f - ty);
            float gv = vproj[((size_t)(st + yi * W + xi)) * D + h * HD + d];
            acc += a * wgt * gv;
          }
        }
      }
    }
  }
  smp[(size_t)q * D + h * HD + d] = f2bf(acc);
}

// ---------------------------------------------------------------------------
extern "C" void kernel_launch(void* const* d_in, const int* in_sizes, int n_in,
                              void* d_out, int out_size, void* d_ws, size_t ws_size,
                              hipStream_t stream) {
  const float* query  = (const float*)d_in[0];
  const float* value  = (const float*)d_in[1];
  const float* qpos   = (const float*)d_in[2];
  const float* refp   = (const float*)d_in[3];
  const float* n1g = (const float*)d_in[6];
  const float* n1b = (const float*)d_in[7];
  const float* Woff = (const float*)d_in[8];
  const float* boff = (const float*)d_in[9];
  const float* Wattn = (const float*)d_in[10];
  const float* battn = (const float*)d_in[11];
  const float* Wval = (const float*)d_in[12];
  const float* bval = (const float*)d_in[13];
  const float* Wout = (const float*)d_in[14];
  const float* bout = (const float*)d_in[15];
  const float* n2g = (const float*)d_in[16];
  const float* n2b = (const float*)d_in[17];
  const float* W1 = (const float*)d_in[18];
  const float* b1 = (const float*)d_in[19];
  const float* W2 = (const float*)d_in[20];
  const float* b2 = (const float*)d_in[21];

  float* out = (float*)d_out;
  char* W = (char*)d_ws;

  // workspace layout (time-overlaid regions)
  short* qp_bf   = (short*)W;                     // 20,480,000 B  [live: ln1 -> offattn gemm]
  float* iden    = (float*)(W + 20480000);        // 40,960,000 B  [live: ln1 -> outproj]
  float* locb    = (float*)(W + 61440000);        // 30,720,000 B  [live: post -> sample]
  float* awb     = (float*)(W + 92160000);        // 15,360,000 B  [live: post -> sample]
  float* res     = (float*)(W + 107520000);       // region C (53,760,000 B)
  float* vprj    = (float*)(W + 107520000);       //   res -> vprj -> h_bf
  short* h_bf    = (short*)(W + 107520000);
  short* val_bf  = (short*)(W + 161280000);       // region D (26,880,000 B)
  short* smp_bf  = (short*)(W + 161280000);       //   val_bf -> smp_bf
  short* mid_bf  = (short*)W;                     // 81,920,000 B overlays qp/iden/locb
  short* WT288   = (short*)(W + 188160000);
  short* WTval   = (short*)(W + 188307456);
  short* WTout   = (short*)(W + 188438528);
  short* WT1     = (short*)(W + 188569600);
  short* WT2     = (short*)(W + 189093888);
  float* bias288 = (float*)(W + 189618176);

  // weight prep
  k_wt<<<(192 * 256 + 255) / 256, 256, 0, stream>>>(Woff, WT288, 256, 192);
  k_wt<<<(96 * 256 + 255) / 256, 256, 0, stream>>>(Wattn, WT288 + 192 * 256, 256, 96);
  k_wt<<<(256 * 256 + 255) / 256, 256, 0, stream>>>(Wval, WTval, 256, 256);
  k_wt<<<(256 * 256 + 255) / 256, 256, 0, stream>>>(Wout, WTout, 256, 256);
  k_wt<<<(1024 * 256 + 255) / 256, 256, 0, stream>>>(W1, WT1, 256, 1024);
  k_wt<<<(256 * 1024 + 255) / 256, 256, 0, stream>>>(W2, WT2, 1024, 256);
  k_catbias<<<1, 320, 0, stream>>>(boff, battn, bias288);

  // LN1 -> iden(f32), qp(bf16)
  k_ln1<<<NQ / 4, 256, 0, stream>>>(query, qpos, n1g, n1b, iden, qp_bf);

  // offsets+attn logits GEMM (N=288)
  k_gemm<0><<<dim3(NQ / 64, 5), 256, 0, stream>>>(qp_bf, WT288, bias288, res,
                                                  nullptr, nullptr, nullptr,
                                                  NQ, 288, 256);
  k_post<<<(NQ * 8 + 255) / 256, 256, 0, stream>>>(res, refp, locb, awb);

  // value proj
  k_cvt<<<(NV * 64 + 255) / 256, 256, 0, stream>>>(value, val_bf, NV * 64);
  k_gemm<0><<<dim3((NV + 63) / 64, 4), 256, 0, stream>>>(val_bf, WTval, bval, vprj,
                                                         nullptr, nullptr, nullptr,
                                                         NV, 256, 256);

  // deformable sampling -> smp(bf16)
  k_sample<<<NQ * NHEAD / 8, 256, 0, stream>>>(vprj, locb, awb, smp_bf);

  // out proj + residuals -> x (d_out)
  k_gemm<2><<<dim3(NQ / 64, 4), 256, 0, stream>>>(smp_bf, WTout, bout, out,
                                                  nullptr, query, iden,
                                                  NQ, 256, 256);

  // LN2 -> h(bf16)
  k_ln2<<<NQ / 4, 256, 0, stream>>>(out, n2g, n2b, h_bf);

  // FFN1: gelu(h@W1+b1) -> mid(bf16)
  k_gemm<1><<<dim3(NQ / 64, 16), 256, 0, stream>>>(h_bf, WT1, b1, nullptr,
                                                   mid_bf, nullptr, nullptr,
                                                   NQ, 1024, 256);

  // FFN2: x += mid@W2+b2 (in place on d_out)
  k_gemm<3><<<dim3(NQ / 64, 4), 256, 0, stream>>>(mid_bf, WT2, b2, out,
                                                  nullptr, nullptr, nullptr,
                                                  NQ, 256, 1024);
}

// Round 3
// 674.389 us; speedup vs baseline: 2.9829x; 1.1212x over previous
//
#include <hip/hip_runtime.h>
#include <hip/hip_bf16.h>
#include <math.h>

#define NQ 40000
#define NV 52500
#define D 256
#define NHEAD 8
#define HD 32

using bf16x8 = __attribute__((ext_vector_type(8))) short;
using f32x4  = __attribute__((ext_vector_type(4))) float;

__device__ __forceinline__ short f2bf(float f) {
  union { __hip_bfloat16 h; short s; } u;
  u.h = __float2bfloat16(f);
  return u.s;
}

// ---------------------------------------------------- weight transpose->bf16
__global__ __launch_bounds__(256) void k_wt(const float* __restrict__ Wm,
                                            short* __restrict__ WT, int K, int N) {
  int idx = blockIdx.x * 256 + threadIdx.x;
  if (idx >= N * K) return;
  int n = idx / K, k = idx - n * K;
  WT[idx] = f2bf(Wm[(size_t)k * N + n]);
}

__global__ void k_catbias(const float* __restrict__ a, const float* __restrict__ b,
                          float* __restrict__ o) {
  int i = threadIdx.x;
  if (i < 192) o[i] = a[i];
  else if (i < 288) o[i] = b[i - 192];
}

// ---------------------------------------------------------------- LN1 + qp
__global__ __launch_bounds__(256) void k_ln1(const float* __restrict__ qin,
                                             const float* __restrict__ qpos,
                                             const float* __restrict__ g,
                                             const float* __restrict__ b,
                                             float* __restrict__ id_out,
                                             short* __restrict__ qp_out) {
  int wave = threadIdx.x >> 6;
  int lane = threadIdx.x & 63;
  int row  = blockIdx.x * 4 + wave;
  float4 x = ((const float4*)(qin + (size_t)row * D))[lane];
  float s  = x.x + x.y + x.z + x.w;
  float ss = x.x*x.x + x.y*x.y + x.z*x.z + x.w*x.w;
  for (int o = 32; o > 0; o >>= 1) { s += __shfl_down(s, o); ss += __shfl_down(ss, o); }
  s  = __shfl(s, 0);
  ss = __shfl(ss, 0);
  float m   = s * (1.0f / 256.0f);
  float var = ss * (1.0f / 256.0f) - m * m;
  float rs  = rsqrtf(var + 1e-5f);
  float4 gg = ((const float4*)g)[lane];
  float4 bb = ((const float4*)b)[lane];
  float4 qn;
  qn.x = (x.x - m) * rs * gg.x + bb.x;
  qn.y = (x.y - m) * rs * gg.y + bb.y;
  qn.z = (x.z - m) * rs * gg.z + bb.z;
  qn.w = (x.w - m) * rs * gg.w + bb.w;
  ((float4*)(id_out + (size_t)row * D))[lane] = qn;
  float4 p = ((const float4*)(qpos + (size_t)row * D))[lane];
  short4 o;
  o.x = f2bf(qn.x + p.x); o.y = f2bf(qn.y + p.y);
  o.z = f2bf(qn.z + p.z); o.w = f2bf(qn.w + p.w);
  ((short4*)(qp_out + (size_t)row * D))[lane] = o;
}

// ----------------------------------------------------------- LN2 -> bf16 h
__global__ __launch_bounds__(256) void k_ln2(const float* __restrict__ xin,
                                             const float* __restrict__ g,
                                             const float* __restrict__ b,
                                             short* __restrict__ h_out) {
  int wave = threadIdx.x >> 6;
  int lane = threadIdx.x & 63;
  int row  = blockIdx.x * 4 + wave;
  float4 x = ((const float4*)(xin + (size_t)row * D))[lane];
  float s  = x.x + x.y + x.z + x.w;
  float ss = x.x*x.x + x.y*x.y + x.z*x.z + x.w*x.w;
  for (int o = 32; o > 0; o >>= 1) { s += __shfl_down(s, o); ss += __shfl_down(ss, o); }
  s  = __shfl(s, 0);
  ss = __shfl(ss, 0);
  float m   = s * (1.0f / 256.0f);
  float var = ss * (1.0f / 256.0f) - m * m;
  float rs  = rsqrtf(var + 1e-5f);
  float4 gg = ((const float4*)g)[lane];
  float4 bb = ((const float4*)b)[lane];
  short4 o;
  o.x = f2bf((x.x - m) * rs * gg.x + bb.x);
  o.y = f2bf((x.y - m) * rs * gg.y + bb.y);
  o.z = f2bf((x.z - m) * rs * gg.z + bb.z);
  o.w = f2bf((x.w - m) * rs * gg.w + bb.w);
  ((short4*)(h_out + (size_t)row * D))[lane] = o;
}

// ----------------------------------------------------------- fp32 -> bf16
__global__ __launch_bounds__(256) void k_cvt(const float* __restrict__ in,
                                             short* __restrict__ out, int n4) {
  int i = blockIdx.x * 256 + threadIdx.x;
  if (i >= n4) return;
  float4 v = ((const float4*)in)[i];
  short4 o;
  o.x = f2bf(v.x); o.y = f2bf(v.y); o.z = f2bf(v.z); o.w = f2bf(v.w);
  ((short4*)out)[i] = o;
}

// --------------------------------------------------------------- MFMA GEMM
// C[M][N] = A[M][K](bf16) @ WT[N][K]^T(bf16) + bias
// EPI: 0 = store f32; 1 = gelu -> bf16; 2 = + R1 + R2 -> f32; 3 = Cf += v;
//      4 = store bf16
template<int EPI>
__global__ __launch_bounds__(256) void k_gemm(const short* __restrict__ A,
                                              const short* __restrict__ WT,
                                              const float* __restrict__ bias,
                                              float* __restrict__ Cf,
                                              short* __restrict__ Cb,
                                              const float* __restrict__ R1,
                                              const float* __restrict__ R2,
                                              int M, int N, int K) {
  __shared__ short Al[64 * 40];
  __shared__ short Bl[64 * 40];
  const int tid = threadIdx.x;
  const int m0 = blockIdx.x * 64, n0 = blockIdx.y * 64;
  const int sr = tid >> 2, sc = (tid & 3) << 3;
  const int lane = tid & 63, w = tid >> 6;
  const int wm = (w >> 1) * 32, wn = (w & 1) * 32;
  const int lr = lane & 15, lk = (lane >> 4) << 3;

  const bf16x8* a0p = (const bf16x8*)&Al[(wm + lr) * 40 + lk];
  const bf16x8* a1p = (const bf16x8*)&Al[(wm + 16 + lr) * 40 + lk];
  const bf16x8* b0p = (const bf16x8*)&Bl[(wn + lr) * 40 + lk];
  const bf16x8* b1p = (const bf16x8*)&Bl[(wn + 16 + lr) * 40 + lk];

  const short* aSrc = (m0 + sr < M) ? A + (size_t)(m0 + sr) * K + sc : nullptr;
  const short* bSrc = (n0 + sr < N) ? WT + (size_t)(n0 + sr) * K + sc : nullptr;

  f32x4 acc00 = {0,0,0,0}, acc01 = {0,0,0,0}, acc10 = {0,0,0,0}, acc11 = {0,0,0,0};

  for (int k0 = 0; k0 < K; k0 += 32) {
    int4 av = {0,0,0,0}, bv = {0,0,0,0};
    if (aSrc) av = *(const int4*)(aSrc + k0);
    if (bSrc) bv = *(const int4*)(bSrc + k0);
    __syncthreads();
    *(int4*)&Al[sr * 40 + sc] = av;
    *(int4*)&Bl[sr * 40 + sc] = bv;
    __syncthreads();
    bf16x8 af0 = *a0p, af1 = *a1p, bf0 = *b0p, bf1 = *b1p;
    acc00 = __builtin_amdgcn_mfma_f32_16x16x32_bf16(af0, bf0, acc00, 0, 0, 0);
    acc01 = __builtin_amdgcn_mfma_f32_16x16x32_bf16(af0, bf1, acc01, 0, 0, 0);
    acc10 = __builtin_amdgcn_mfma_f32_16x16x32_bf16(af1, bf0, acc10, 0, 0, 0);
    acc11 = __builtin_amdgcn_mfma_f32_16x16x32_bf16(af1, bf1, acc11, 0, 0, 0);
  }

  const int er = (lane >> 4) << 2;
  const int ec = lane & 15;
#pragma unroll
  for (int i = 0; i < 2; ++i) {
#pragma unroll
    for (int j = 0; j < 2; ++j) {
      f32x4 acc = (i == 0) ? (j == 0 ? acc00 : acc01) : (j == 0 ? acc10 : acc11);
      int col = n0 + wn + j * 16 + ec;
      if (col >= N) continue;
      float bcol = bias[col];
#pragma unroll
      for (int r = 0; r < 4; ++r) {
        int row = m0 + wm + i * 16 + er + r;
        if (row >= M) continue;
        float v = acc[r] + bcol;
        size_t off = (size_t)row * N + col;
        if (EPI == 0) {
          Cf[off] = v;
        } else if (EPI == 1) {
          Cb[off] = f2bf(0.5f * v * (1.0f + erff(v * 0.70710678118f)));
        } else if (EPI == 2) {
          Cf[off] = v + R1[off] + R2[off];
        } else if (EPI == 3) {
          Cf[off] += v;
        } else {
          Cb[off] = f2bf(v);
        }
      }
    }
  }
}

// --------------------------------------------- softmax + loc from res rows
__global__ __launch_bounds__(256) void k_post(const float* __restrict__ res,
                                              const float* __restrict__ refp,
                                              float* __restrict__ loc_out,
                                              float* __restrict__ aw_out) {
  int t = blockIdx.x * 256 + threadIdx.x;
  if (t >= NQ * 8) return;
  int q = t >> 3, h = t & 7;
  const float* rr = res + (size_t)q * 288;
  const float* lg = rr + 192 + h * 12;
  float mx = lg[0];
#pragma unroll
  for (int i = 1; i < 12; ++i) mx = fmaxf(mx, lg[i]);
  float e[12]; float sum = 0.0f;
#pragma unroll
  for (int i = 0; i < 12; ++i) { e[i] = expf(lg[i] - mx); sum += e[i]; }
  float inv = 1.0f / sum;
#pragma unroll
  for (int i = 0; i < 12; ++i)
    aw_out[(size_t)q * 96 + h * 12 + i] = e[i] * inv;

  const float dims[3] = {200.0f, 100.0f, 50.0f};
#pragma unroll
  for (int l = 0; l < 3; ++l) {
    float rx = refp[((size_t)q * 3 + l) * 2 + 0];
    float ry = refp[((size_t)q * 3 + l) * 2 + 1];
    float invd = 1.0f / dims[l];
#pragma unroll
    for (int p = 0; p < 4; ++p) {
      int j = ((h * 3 + l) * 4 + p) * 2;
      loc_out[(size_t)q * 192 + j + 0] = rx + rr[j + 0] * invd;
      loc_out[(size_t)q * 192 + j + 1] = ry + rr[j + 1] * invd;
    }
  }
}

// ----------------------------------------------------------- deform sampling
// One 64-lane wave per (q,h). lane = tap(2b: dy,dx) * chanpair(4b).
// Per point: one uint load (2 bf16 channels) per lane covers the full 2x2
// bilinear footprint across the wave. Tap partials reduced by shfl_xor.
__global__ __launch_bounds__(256) void k_sample(const short* __restrict__ vproj,
                                                const float* __restrict__ loc,
                                                const float* __restrict__ aw,
                                                short* __restrict__ smp) {
  const int lane = threadIdx.x & 63;
  const int qh   = blockIdx.x * 4 + (threadIdx.x >> 6);
  const int q = qh >> 3, h = qh & 7;
  const int tap = lane >> 4;       // 0..3
  const int cp  = lane & 15;       // channel pair 0..15
  const int dx = tap & 1, dy = tap >> 1;
  const float fdx = (float)dx, fdy = (float)dy;

  const float* locq = loc + (size_t)q * 192 + h * 24;
  const float* awq  = aw  + (size_t)q * 96  + h * 12;
  const short* vb   = vproj + h * HD + (cp << 1);

  float acc0 = 0.0f, acc1 = 0.0f;
  const int   Dim[3] = {200, 100, 50};
  const int   St[3]  = {0, 40000, 50000};

#pragma unroll
  for (int l = 0; l < 3; ++l) {
    const int W = Dim[l], H = Dim[l], st = St[l];
    const float fW = (float)W, fH = (float)H;
#pragma unroll
    for (int p = 0; p < 4; ++p) {
      float lx = locq[l * 8 + p * 2];
      float ly = locq[l * 8 + p * 2 + 1];
      float a  = awq[l * 4 + p];
      float fx = lx * fW - 0.5f;
      float fy = ly * fH - 0.5f;
      float x0f = floorf(fx), y0f = floorf(fy);
      float tx = fx - x0f, ty = fy - y0f;
      int x0 = (int)x0f, y0 = (int)y0f;
      int xi = x0 + dx, yi = y0 + dy;
      bool valid = ((unsigned)xi < (unsigned)W) & ((unsigned)yi < (unsigned)H);
      float wx = fdx * tx + (1.0f - fdx) * (1.0f - tx);
      float wy = fdy * ty + (1.0f - fdy) * (1.0f - ty);
      float wgt = valid ? a * wx * wy : 0.0f;
      int idx = valid ? (st + yi * W + xi) : 0;
      unsigned v = *(const unsigned*)(vb + (size_t)idx * D);
      float c0 = __uint_as_float(v << 16);
      float c1 = __uint_as_float(v & 0xffff0000u);
      acc0 = fmaf(wgt, c0, acc0);
      acc1 = fmaf(wgt, c1, acc1);
    }
  }

  // reduce the 4 taps (lanes differing in bits 4,5)
  acc0 += __shfl_xor(acc0, 16);
  acc0 += __shfl_xor(acc0, 32);
  acc1 += __shfl_xor(acc1, 16);
  acc1 += __shfl_xor(acc1, 32);

  if (lane < 16) {
    unsigned o = (unsigned)(unsigned short)f2bf(acc0) |
                 ((unsigned)(unsigned short)f2bf(acc1) << 16);
    *(unsigned*)(smp + (size_t)q * D + h * HD + (cp << 1)) = o;
  }
}

// ---------------------------------------------------------------------------
extern "C" void kernel_launch(void* const* d_in, const int* in_sizes, int n_in,
                              void* d_out, int out_size, void* d_ws, size_t ws_size,
                              hipStream_t stream) {
  const float* query  = (const float*)d_in[0];
  const float* value  = (const float*)d_in[1];
  const float* qpos   = (const float*)d_in[2];
  const float* refp   = (const float*)d_in[3];
  const float* n1g = (const float*)d_in[6];
  const float* n1b = (const float*)d_in[7];
  const float* Woff = (const float*)d_in[8];
  const float* boff = (const float*)d_in[9];
  const float* Wattn = (const float*)d_in[10];
  const float* battn = (const float*)d_in[11];
  const float* Wval = (const float*)d_in[12];
  const float* bval = (const float*)d_in[13];
  const float* Wout = (const float*)d_in[14];
  const float* bout = (const float*)d_in[15];
  const float* n2g = (const float*)d_in[16];
  const float* n2b = (const float*)d_in[17];
  const float* W1 = (const float*)d_in[18];
  const float* b1 = (const float*)d_in[19];
  const float* W2 = (const float*)d_in[20];
  const float* b2 = (const float*)d_in[21];

  float* out = (float*)d_out;
  char* Wb = (char*)d_ws;

  // workspace layout (time-overlaid regions)
  short* qp_bf   = (short*)Wb;                    // [0,20.48M)   ln1 -> offattn
  float* iden    = (float*)(Wb + 20480000);       // [20.48M,61.44M) ln1 -> outproj
  float* locb    = (float*)(Wb + 61440000);       // [61.44M,92.16M) post -> sample
  float* awb     = (float*)(Wb + 92160000);       // [92.16M,107.52M) post -> sample
  float* res     = (float*)(Wb + 107520000);      // region C (46.08 MB)
  short* vprj_bf = (short*)(Wb + 107520000);      //   res -> vprj -> h_bf
  short* h_bf    = (short*)(Wb + 107520000);
  short* val_bf  = (short*)(Wb + 153600000);      // region D (26.88 MB)
  short* smp_bf  = (short*)(Wb + 153600000);      //   val_bf -> smp_bf
  short* mid_bf  = (short*)Wb;                    // 81.92 MB overlays qp/iden/locb
  short* WT288   = (short*)(Wb + 188160000);
  short* WTval   = (short*)(Wb + 188307456);
  short* WTout   = (short*)(Wb + 188438528);
  short* WT1     = (short*)(Wb + 188569600);
  short* WT2     = (short*)(Wb + 189093888);
  float* bias288 = (float*)(Wb + 189618176);

  // weight prep
  k_wt<<<(192 * 256 + 255) / 256, 256, 0, stream>>>(Woff, WT288, 256, 192);
  k_wt<<<(96 * 256 + 255) / 256, 256, 0, stream>>>(Wattn, WT288 + 192 * 256, 256, 96);
  k_wt<<<(256 * 256 + 255) / 256, 256, 0, stream>>>(Wval, WTval, 256, 256);
  k_wt<<<(256 * 256 + 255) / 256, 256, 0, stream>>>(Wout, WTout, 256, 256);
  k_wt<<<(1024 * 256 + 255) / 256, 256, 0, stream>>>(W1, WT1, 256, 1024);
  k_wt<<<(256 * 1024 + 255) / 256, 256, 0, stream>>>(W2, WT2, 1024, 256);
  k_catbias<<<1, 320, 0, stream>>>(boff, battn, bias288);

  // LN1 -> iden(f32), qp(bf16)
  k_ln1<<<NQ / 4, 256, 0, stream>>>(query, qpos, n1g, n1b, iden, qp_bf);

  // offsets+attn logits GEMM (N=288)
  k_gemm<0><<<dim3(NQ / 64, 5), 256, 0, stream>>>(qp_bf, WT288, bias288, res,
                                                  nullptr, nullptr, nullptr,
                                                  NQ, 288, 256);
  k_post<<<(NQ * 8 + 255) / 256, 256, 0, stream>>>(res, refp, locb, awb);

  // value proj -> bf16
  k_cvt<<<(NV * 64 + 255) / 256, 256, 0, stream>>>(value, val_bf, NV * 64);
  k_gemm<4><<<dim3((NV + 63) / 64, 4), 256, 0, stream>>>(val_bf, WTval, bval, nullptr,
                                                         vprj_bf, nullptr, nullptr,
                                                         NV, 256, 256);

  // deformable sampling -> smp(bf16)
  k_sample<<<NQ * NHEAD / 4, 256, 0, stream>>>(vprj_bf, locb, awb, smp_bf);

  // out proj + residuals -> x (d_out)
  k_gemm<2><<<dim3(NQ / 64, 4), 256, 0, stream>>>(smp_bf, WTout, bout, out,
                                                  nullptr, query, iden,
                                                  NQ, 256, 256);

  // LN2 -> h(bf16)
  k_ln2<<<NQ / 4, 256, 0, stream>>>(out, n2g, n2b, h_bf);

  // FFN1: gelu(h@W1+b1) -> mid(bf16)
  k_gemm<1><<<dim3(NQ / 64, 16), 256, 0, stream>>>(h_bf, WT1, b1, nullptr,
                                                   mid_bf, nullptr, nullptr,
                                                   NQ, 1024, 256);

  // FFN2: x += mid@W2+b2 (in place on d_out)
  k_gemm<3><<<dim3(NQ / 64, 4), 256, 0, stream>>>(mid_bf, WT2, b2, out,
                                                  nullptr, nullptr, nullptr,
                                                  NQ, 256, 1024);
}

// Round 4
// 483.144 us; speedup vs baseline: 4.1637x; 1.3958x over previous
//
#include <hip/hip_runtime.h>
#include <hip/hip_bf16.h>
#include <math.h>

#define NQ 40000
#define NV 52500
#define D 256
#define NHEAD 8
#define HD 32

using bf16x8 = __attribute__((ext_vector_type(8))) short;
using f32x4  = __attribute__((ext_vector_type(4))) float;

__device__ __forceinline__ short f2bf(float f) {
  union { __hip_bfloat16 h; short s; } u;
  u.h = __float2bfloat16(f);
  return u.s;
}
__device__ __forceinline__ unsigned pack2(float lo, float hi) {
  return (unsigned)(unsigned short)f2bf(lo) |
         ((unsigned)(unsigned short)f2bf(hi) << 16);
}

// ---------------------------------------------------- weight transpose->bf16
__global__ __launch_bounds__(256) void k_wt(const float* __restrict__ Wm,
                                            short* __restrict__ WT, int K, int N) {
  int idx = blockIdx.x * 256 + threadIdx.x;
  if (idx >= N * K) return;
  int n = idx / K, k = idx - n * K;
  WT[idx] = f2bf(Wm[(size_t)k * N + n]);
}

__global__ void k_catbias(const float* __restrict__ a, const float* __restrict__ b,
                          float* __restrict__ o) {
  int i = threadIdx.x;
  if (i < 192) o[i] = a[i];
  else if (i < 288) o[i] = b[i - 192];
}

// ---------------------------------------------------------------- LN1 + qp
__global__ __launch_bounds__(256) void k_ln1(const float* __restrict__ qin,
                                             const float* __restrict__ qpos,
                                             const float* __restrict__ g,
                                             const float* __restrict__ b,
                                             float* __restrict__ id_out,
                                             short* __restrict__ qp_out) {
  int wave = threadIdx.x >> 6;
  int lane = threadIdx.x & 63;
  int row  = blockIdx.x * 4 + wave;
  float4 x = ((const float4*)(qin + (size_t)row * D))[lane];
  float s  = x.x + x.y + x.z + x.w;
  float ss = x.x*x.x + x.y*x.y + x.z*x.z + x.w*x.w;
  for (int o = 32; o > 0; o >>= 1) { s += __shfl_down(s, o); ss += __shfl_down(ss, o); }
  s  = __shfl(s, 0);
  ss = __shfl(ss, 0);
  float m   = s * (1.0f / 256.0f);
  float var = ss * (1.0f / 256.0f) - m * m;
  float rs  = rsqrtf(var + 1e-5f);
  float4 gg = ((const float4*)g)[lane];
  float4 bb = ((const float4*)b)[lane];
  float4 qn;
  qn.x = (x.x - m) * rs * gg.x + bb.x;
  qn.y = (x.y - m) * rs * gg.y + bb.y;
  qn.z = (x.z - m) * rs * gg.z + bb.z;
  qn.w = (x.w - m) * rs * gg.w + bb.w;
  ((float4*)(id_out + (size_t)row * D))[lane] = qn;
  float4 p = ((const float4*)(qpos + (size_t)row * D))[lane];
  short4 o;
  o.x = f2bf(qn.x + p.x); o.y = f2bf(qn.y + p.y);
  o.z = f2bf(qn.z + p.z); o.w = f2bf(qn.w + p.w);
  ((short4*)(qp_out + (size_t)row * D))[lane] = o;
}

// ----------------------------------------------------------- LN2 -> bf16 h
__global__ __launch_bounds__(256) void k_ln2(const float* __restrict__ xin,
                                             const float* __restrict__ g,
                                             const float* __restrict__ b,
                                             short* __restrict__ h_out) {
  int wave = threadIdx.x >> 6;
  int lane = threadIdx.x & 63;
  int row  = blockIdx.x * 4 + wave;
  float4 x = ((const float4*)(xin + (size_t)row * D))[lane];
  float s  = x.x + x.y + x.z + x.w;
  float ss = x.x*x.x + x.y*x.y + x.z*x.z + x.w*x.w;
  for (int o = 32; o > 0; o >>= 1) { s += __shfl_down(s, o); ss += __shfl_down(ss, o); }
  s  = __shfl(s, 0);
  ss = __shfl(ss, 0);
  float m   = s * (1.0f / 256.0f);
  float var = ss * (1.0f / 256.0f) - m * m;
  float rs  = rsqrtf(var + 1e-5f);
  float4 gg = ((const float4*)g)[lane];
  float4 bb = ((const float4*)b)[lane];
  short4 o;
  o.x = f2bf((x.x - m) * rs * gg.x + bb.x);
  o.y = f2bf((x.y - m) * rs * gg.y + bb.y);
  o.z = f2bf((x.z - m) * rs * gg.z + bb.z);
  o.w = f2bf((x.w - m) * rs * gg.w + bb.w);
  ((short4*)(h_out + (size_t)row * D))[lane] = o;
}

// --------------------------------------------------------------- MFMA GEMM
// C[M][N] = A[M][K](bf16, or f32 if CVTA) @ WT[N][K]^T(bf16) + bias
// EPI: 0 = store f32; 1 = gelu -> bf16; 2 = + R1 + R2 -> f32; 3 = Cf += v;
//      4 = store bf16
template<int EPI, int CVTA>
__global__ __launch_bounds__(256) void k_gemm(const void* __restrict__ Ain,
                                              const short* __restrict__ WT,
                                              const float* __restrict__ bias,
                                              float* __restrict__ Cf,
                                              short* __restrict__ Cb,
                                              const float* __restrict__ R1,
                                              const float* __restrict__ R2,
                                              int M, int N, int K) {
  __shared__ short Al[64 * 40];
  __shared__ short Bl[64 * 40];
  const int tid = threadIdx.x;
  const int m0 = blockIdx.x * 64, n0 = blockIdx.y * 64;
  const int sr = tid >> 2, sc = (tid & 3) << 3;
  const int lane = tid & 63, w = tid >> 6;
  const int wm = (w >> 1) * 32, wn = (w & 1) * 32;
  const int lr = lane & 15, lk = (lane >> 4) << 3;

  const bf16x8* a0p = (const bf16x8*)&Al[(wm + lr) * 40 + lk];
  const bf16x8* a1p = (const bf16x8*)&Al[(wm + 16 + lr) * 40 + lk];
  const bf16x8* b0p = (const bf16x8*)&Bl[(wn + lr) * 40 + lk];
  const bf16x8* b1p = (const bf16x8*)&Bl[(wn + 16 + lr) * 40 + lk];

  const short* aSrcS = nullptr;
  const float* aSrcF = nullptr;
  if (m0 + sr < M) {
    if (CVTA) aSrcF = (const float*)Ain + (size_t)(m0 + sr) * K + sc;
    else      aSrcS = (const short*)Ain + (size_t)(m0 + sr) * K + sc;
  }
  const short* bSrc = (n0 + sr < N) ? WT + (size_t)(n0 + sr) * K + sc : nullptr;

  f32x4 acc00 = {0,0,0,0}, acc01 = {0,0,0,0}, acc10 = {0,0,0,0}, acc11 = {0,0,0,0};

  for (int k0 = 0; k0 < K; k0 += 32) {
    int4 av = {0,0,0,0}, bv = {0,0,0,0};
    if (CVTA) {
      if (aSrcF) {
        float4 f0 = *(const float4*)(aSrcF + k0);
        float4 f1 = *(const float4*)(aSrcF + k0 + 4);
        av.x = pack2(f0.x, f0.y); av.y = pack2(f0.z, f0.w);
        av.z = pack2(f1.x, f1.y); av.w = pack2(f1.z, f1.w);
      }
    } else {
      if (aSrcS) av = *(const int4*)(aSrcS + k0);
    }
    if (bSrc) bv = *(const int4*)(bSrc + k0);
    __syncthreads();
    *(int4*)&Al[sr * 40 + sc] = av;
    *(int4*)&Bl[sr * 40 + sc] = bv;
    __syncthreads();
    bf16x8 af0 = *a0p, af1 = *a1p, bf0 = *b0p, bf1 = *b1p;
    acc00 = __builtin_amdgcn_mfma_f32_16x16x32_bf16(af0, bf0, acc00, 0, 0, 0);
    acc01 = __builtin_amdgcn_mfma_f32_16x16x32_bf16(af0, bf1, acc01, 0, 0, 0);
    acc10 = __builtin_amdgcn_mfma_f32_16x16x32_bf16(af1, bf0, acc10, 0, 0, 0);
    acc11 = __builtin_amdgcn_mfma_f32_16x16x32_bf16(af1, bf1, acc11, 0, 0, 0);
  }

  const int er = (lane >> 4) << 2;
  const int ec = lane & 15;
#pragma unroll
  for (int i = 0; i < 2; ++i) {
#pragma unroll
    for (int j = 0; j < 2; ++j) {
      f32x4 acc = (i == 0) ? (j == 0 ? acc00 : acc01) : (j == 0 ? acc10 : acc11);
      int col = n0 + wn + j * 16 + ec;
      if (col >= N) continue;
      float bcol = bias[col];
#pragma unroll
      for (int r = 0; r < 4; ++r) {
        int row = m0 + wm + i * 16 + er + r;
        if (row >= M) continue;
        float v = acc[r] + bcol;
        size_t off = (size_t)row * N + col;
        if (EPI == 0) {
          Cf[off] = v;
        } else if (EPI == 1) {
          Cb[off] = f2bf(0.5f * v * (1.0f + erff(v * 0.70710678118f)));
        } else if (EPI == 2) {
          Cf[off] = v + R1[off] + R2[off];
        } else if (EPI == 3) {
          Cf[off] += v;
        } else {
          Cb[off] = f2bf(v);
        }
      }
    }
  }
}

// ---------------- softmax + per-point sampling meta: idx0 + 4 bf16 tap wgts
__global__ __launch_bounds__(256) void k_post(const float* __restrict__ res,
                                              const float* __restrict__ refp,
                                              int* __restrict__ idxA,
                                              unsigned short* __restrict__ wA) {
  int t = blockIdx.x * 256 + threadIdx.x;
  if (t >= NQ * 8) return;
  int q = t >> 3, h = t & 7;
  const float* rr = res + (size_t)q * 288;
  const float* lg = rr + 192 + h * 12;
  float mx = lg[0];
#pragma unroll
  for (int i = 1; i < 12; ++i) mx = fmaxf(mx, lg[i]);
  float e[12]; float sum = 0.0f;
#pragma unroll
  for (int i = 0; i < 12; ++i) { e[i] = expf(lg[i] - mx); sum += e[i]; }
  float inv = 1.0f / sum;

  const float dims[3] = {200.0f, 100.0f, 50.0f};
  const int   sts[3]  = {0, 40000, 50000};
#pragma unroll
  for (int l = 0; l < 3; ++l) {
    const int W = (int)dims[l];
    const float fW = dims[l];
    float rx = refp[((size_t)q * 3 + l) * 2 + 0];
    float ry = refp[((size_t)q * 3 + l) * 2 + 1];
    float invd = 1.0f / fW;
#pragma unroll
    for (int p = 0; p < 4; ++p) {
      int j = ((h * 3 + l) * 4 + p) * 2;
      float lx = rx + rr[j + 0] * invd;
      float ly = ry + rr[j + 1] * invd;
      float fx = lx * fW - 0.5f;
      float fy = ly * fW - 0.5f;
      float x0f = floorf(fx), y0f = floorf(fy);
      float tx = fx - x0f, ty = fy - y0f;
      int x0 = (int)x0f, y0 = (int)y0f;
      bool vx0 = (unsigned)x0       < (unsigned)W;
      bool vx1 = (unsigned)(x0 + 1) < (unsigned)W;
      bool vy0 = (unsigned)y0       < (unsigned)W;
      bool vy1 = (unsigned)(y0 + 1) < (unsigned)W;
      float a = e[l * 4 + p] * inv;
      float w00 = (vx0 && vy0) ? a * (1.0f - tx) * (1.0f - ty) : 0.0f;
      float w01 = (vx1 && vy0) ? a * tx * (1.0f - ty) : 0.0f;
      float w10 = (vx0 && vy1) ? a * (1.0f - tx) * ty : 0.0f;
      float w11 = (vx1 && vy1) ? a * tx * ty : 0.0f;
      int pidx = t * 12 + l * 4 + p;
      idxA[pidx] = sts[l] + y0 * W + x0;
      short4 wpk;
      wpk.x = f2bf(w00); wpk.y = f2bf(w01);
      wpk.z = f2bf(w10); wpk.w = f2bf(w11);
      *(short4*)(wA + (size_t)pidx * 4) = wpk;
    }
  }
}

// ----------------------------------------------------------- deform sampling
// One 64-lane wave per (q,h). lane = point(2b) x tap(2b) x chan-oct(2b).
// 3 iterations (one per level); each iteration: 2 meta loads + 1 dwordx4
// gather covering 4 points' full 2x2 footprints. Final 4-level shfl reduce.
__global__ __launch_bounds__(256) void k_sample(const short* __restrict__ vproj,
                                                const int* __restrict__ idxA,
                                                const unsigned short* __restrict__ wA,
                                                short* __restrict__ smp) {
  const int lane = threadIdx.x & 63;
  const int qh   = blockIdx.x * 4 + (threadIdx.x >> 6);
  const int h = qh & 7;
  const int pg  = lane >> 4;         // point in level
  const int tap = (lane >> 2) & 3;   // dy,dx
  const int cq  = lane & 3;          // channel oct (8 ch)
  const int dy = tap >> 1, dx = tap & 1;
  const short* vb = vproj + h * HD + cq * 8;

  float acc[8];
#pragma unroll
  for (int j = 0; j < 8; ++j) acc[j] = 0.0f;

  const int Dim[3] = {200, 100, 50};
#pragma unroll
  for (int l = 0; l < 3; ++l) {
    const int W = Dim[l];
    const int tapoff = dy * W + dx;
    int pidx = qh * 12 + l * 4 + pg;
    int idx = idxA[pidx] + tapoff;
    idx = min(max(idx, 0), NV - 1);
    float wgt = __uint_as_float((unsigned)wA[(size_t)pidx * 4 + tap] << 16);
    uint4 v = *(const uint4*)(vb + (size_t)idx * D);
    acc[0] = fmaf(wgt, __uint_as_float(v.x << 16),        acc[0]);
    acc[1] = fmaf(wgt, __uint_as_float(v.x & 0xffff0000u), acc[1]);
    acc[2] = fmaf(wgt, __uint_as_float(v.y << 16),        acc[2]);
    acc[3] = fmaf(wgt, __uint_as_float(v.y & 0xffff0000u), acc[3]);
    acc[4] = fmaf(wgt, __uint_as_float(v.z << 16),        acc[4]);
    acc[5] = fmaf(wgt, __uint_as_float(v.z & 0xffff0000u), acc[5]);
    acc[6] = fmaf(wgt, __uint_as_float(v.w << 16),        acc[6]);
    acc[7] = fmaf(wgt, __uint_as_float(v.w & 0xffff0000u), acc[7]);
  }

  // reduce over taps (lane bits 2,3) and points (lane bits 4,5)
#pragma unroll
  for (int off = 4; off <= 32; off <<= 1) {
#pragma unroll
    for (int j = 0; j < 8; ++j) acc[j] += __shfl_xor(acc[j], off);
  }

  if (lane < 4) {
    uint4 o;
    o.x = pack2(acc[0], acc[1]);
    o.y = pack2(acc[2], acc[3]);
    o.z = pack2(acc[4], acc[5]);
    o.w = pack2(acc[6], acc[7]);
    *(uint4*)(smp + (size_t)qh * HD + cq * 8) = o;
  }
}

// ---------------------------------------------------------------------------
extern "C" void kernel_launch(void* const* d_in, const int* in_sizes, int n_in,
                              void* d_out, int out_size, void* d_ws, size_t ws_size,
                              hipStream_t stream) {
  const float* query  = (const float*)d_in[0];
  const float* value  = (const float*)d_in[1];
  const float* qpos   = (const float*)d_in[2];
  const float* refp   = (const float*)d_in[3];
  const float* n1g = (const float*)d_in[6];
  const float* n1b = (const float*)d_in[7];
  const float* Woff = (const float*)d_in[8];
  const float* boff = (const float*)d_in[9];
  const float* Wattn = (const float*)d_in[10];
  const float* battn = (const float*)d_in[11];
  const float* Wval = (const float*)d_in[12];
  const float* bval = (const float*)d_in[13];
  const float* Wout = (const float*)d_in[14];
  const float* bout = (const float*)d_in[15];
  const float* n2g = (const float*)d_in[16];
  const float* n2b = (const float*)d_in[17];
  const float* W1 = (const float*)d_in[18];
  const float* b1 = (const float*)d_in[19];
  const float* W2 = (const float*)d_in[20];
  const float* b2 = (const float*)d_in[21];

  float* out = (float*)d_out;
  char* Wb = (char*)d_ws;

  // workspace layout (time-overlaid; ~156 MB total)
  short* qp_bf   = (short*)Wb;                    // [0,20.48M)   ln1 -> gemm288
  float* iden    = (float*)(Wb + 20480000);       // [20.48M,61.44M) ln1 -> outproj
  int*   idxA    = (int*)(Wb + 61440000);         // [61.44M,76.8M)  post -> sample
  unsigned short* wA = (unsigned short*)(Wb + 76800000); // [76.8M,107.52M)
  float* res     = (float*)(Wb + 107520000);      // [107.52M,153.6M) gemm288 -> post
  short* vprj_bf = (short*)(Wb + 107520000);      // [107.52M,134.4M) vproj -> sample
  short* h_bf    = (short*)(Wb + 107520000);      // [107.52M,128M)   ln2 -> ffn1
  short* smp_bf  = (short*)(Wb + 134400000);      // [134.4M,154.88M) sample -> outproj
  short* mid_bf  = (short*)Wb;                    // [0,81.92M) ffn1 -> ffn2
  short* WT288   = (short*)(Wb + 154880000);
  short* WTval   = (short*)(Wb + 155027456);
  short* WTout   = (short*)(Wb + 155158528);
  short* WT1     = (short*)(Wb + 155289600);
  short* WT2     = (short*)(Wb + 155813888);
  float* bias288 = (float*)(Wb + 156338176);

  // weight prep
  k_wt<<<(192 * 256 + 255) / 256, 256, 0, stream>>>(Woff, WT288, 256, 192);
  k_wt<<<(96 * 256 + 255) / 256, 256, 0, stream>>>(Wattn, WT288 + 192 * 256, 256, 96);
  k_wt<<<(256 * 256 + 255) / 256, 256, 0, stream>>>(Wval, WTval, 256, 256);
  k_wt<<<(256 * 256 + 255) / 256, 256, 0, stream>>>(Wout, WTout, 256, 256);
  k_wt<<<(1024 * 256 + 255) / 256, 256, 0, stream>>>(W1, WT1, 256, 1024);
  k_wt<<<(256 * 1024 + 255) / 256, 256, 0, stream>>>(W2, WT2, 1024, 256);
  k_catbias<<<1, 320, 0, stream>>>(boff, battn, bias288);

  // LN1 -> iden(f32), qp(bf16)
  k_ln1<<<NQ / 4, 256, 0, stream>>>(query, qpos, n1g, n1b, iden, qp_bf);

  // offsets+attn logits GEMM (N=288)
  k_gemm<0,0><<<dim3(NQ / 64, 5), 256, 0, stream>>>(qp_bf, WT288, bias288, res,
                                                    nullptr, nullptr, nullptr,
                                                    NQ, 288, 256);
  // softmax + sampling meta
  k_post<<<(NQ * 8 + 255) / 256, 256, 0, stream>>>(res, refp, idxA, wA);

  // value proj (fused f32->bf16 A staging) -> bf16
  k_gemm<4,1><<<dim3((NV + 63) / 64, 4), 256, 0, stream>>>(value, WTval, bval, nullptr,
                                                           vprj_bf, nullptr, nullptr,
                                                           NV, 256, 256);

  // deformable sampling -> smp(bf16)
  k_sample<<<NQ * NHEAD / 4, 256, 0, stream>>>(vprj_bf, idxA, wA, smp_bf);

  // out proj + residuals -> x (d_out)
  k_gemm<2,0><<<dim3(NQ / 64, 4), 256, 0, stream>>>(smp_bf, WTout, bout, out,
                                                    nullptr, query, iden,
                                                    NQ, 256, 256);

  // LN2 -> h(bf16)
  k_ln2<<<NQ / 4, 256, 0, stream>>>(out, n2g, n2b, h_bf);

  // FFN1: gelu(h@W1+b1) -> mid(bf16)
  k_gemm<1,0><<<dim3(NQ / 64, 16), 256, 0, stream>>>(h_bf, WT1, b1, nullptr,
                                                     mid_bf, nullptr, nullptr,
                                                     NQ, 1024, 256);

  // FFN2: x += mid@W2+b2 (in place on d_out)
  k_gemm<3,0><<<dim3(NQ / 64, 4), 256, 0, stream>>>(mid_bf, WT2, b2, out,
                                                    nullptr, nullptr, nullptr,
                                                    NQ, 256, 1024);
}